// Round 9
// baseline (257.082 us; speedup 1.0000x reference)
//
#include <hip/hip_runtime.h>
#include <hip/hip_cooperative_groups.h>
#include <math.h>

namespace cg = cooperative_groups;

// B=8, L=4096, D=64, M=64, masked=1 (fixed by setup_inputs)
#define BB 8
#define LL 4096
#define DD 64
#define SS 64
#define NCHUNK 64
#define STATE 4160  // 64x64 KV^T rows (d-major) + 64 N values

typedef __attribute__((ext_vector_type(8))) short s16x8;
typedef __attribute__((ext_vector_type(8))) unsigned short u16x8;
typedef __attribute__((ext_vector_type(4))) float f32x4;

#define MFMA(a, b, c) __builtin_amdgcn_mfma_f32_16x16x32_bf16((a), (b), (c), 0, 0, 0)

static __device__ __forceinline__ unsigned short f2bf(float x) {
  unsigned int u = __builtin_bit_cast(unsigned int, x);
  u += 0x7FFFu + ((u >> 16) & 1u);
  return (unsigned short)(u >> 16);
}
static __device__ __forceinline__ float bf2f(unsigned short h) {
  unsigned int u = ((unsigned int)h) << 16;
  return __builtin_bit_cast(float, u);
}

// LDS bf16 tile, row-major 64 cols, XOR-swizzled: elem (r,k) at r*64 + (k ^ ((r&7)<<3)).
// Frag: row r = row0 + (lane&15), k = ks*32 + (lane>>4)*8 .. +8.
static __device__ __forceinline__ s16x8 ld_frag(const unsigned short* base, int row0, int ks) {
  const int lane = threadIdx.x & 63;
  const int r = row0 + (lane & 15);
  const int idx = r * 64 + ((ks * 32 + ((lane & 48) >> 1)) ^ ((r & 7) << 3));
  return *(const s16x8*)(base + idx);
}

// Stage a 64x64 f32 global tile into hi/lo bf16 LDS tiles (swizzled). Coalesced.
static __device__ __forceinline__ void stage_hl(unsigned short* __restrict__ Sh,
                                                unsigned short* __restrict__ Sl,
                                                const float* __restrict__ src, int tid) {
#pragma unroll
  for (int it = 0; it < 2; ++it) {
    const int g = tid + it * 256;
    const int row = g >> 3;
    const int c0 = (g & 7) * 8;
    const float4 x0 = *(const float4*)(src + row * 64 + c0);
    const float4 x1 = *(const float4*)(src + row * 64 + c0 + 4);
    const float xs[8] = {x0.x, x0.y, x0.z, x0.w, x1.x, x1.y, x1.z, x1.w};
    u16x8 h, l;
#pragma unroll
    for (int k = 0; k < 8; ++k) {
      const unsigned short hh = f2bf(xs[k]);
      h[k] = hh;
      l[k] = f2bf(xs[k] - bf2f(hh));
    }
    const int idx = row * 64 + (c0 ^ ((row & 7) << 3));
    *(u16x8*)(Sh + idx) = h;
    *(u16x8*)(Sl + idx) = l;
  }
}

// Stage full 64x64 V f32 tile (coalesced).
static __device__ __forceinline__ void stage_vfull(float* __restrict__ F, const float* __restrict__ src,
                                                   int tid) {
#pragma unroll
  for (int it = 0; it < 4; ++it) {
    const int g = tid + it * 256;
    const int row = g >> 4;
    const int col = (g & 15) * 4;
    *(float4*)(F + row * 64 + col) = *(const float4*)(src + row * 64 + col);
  }
}

// Stage a linear bf16 [64][64] global image into a swizzled LDS tile. Coalesced. (fallback path)
static __device__ __forceinline__ void stage_img(unsigned short* __restrict__ S,
                                                 const unsigned short* __restrict__ src, int tid) {
#pragma unroll
  for (int it = 0; it < 2; ++it) {
    const int g = tid + it * 256;
    const int row = g >> 3;
    const int c0 = (g & 7) * 8;
    *(u16x8*)(S + row * 64 + (c0 ^ ((row & 7) << 3))) = *(const u16x8*)(src + row * 64 + c0);
  }
}

// Transpose 32 rows of f32 scratch into VT hi/lo bf16 tiles: VT[d][t] (swizzled).
static __device__ __forceinline__ void vtrans_half(unsigned short* __restrict__ Gh,
                                                   unsigned short* __restrict__ Hl,
                                                   const float* __restrict__ F, int tid, int half) {
  const int d = tid & 63;
  const int tb = (tid >> 6) * 8;
  float v[8];
#pragma unroll
  for (int k = 0; k < 8; ++k) v[k] = F[(tb + k) * 64 + d];
  u16x8 hh, ll;
#pragma unroll
  for (int k = 0; k < 8; ++k) {
    const unsigned short h = f2bf(v[k]);
    hh[k] = h;
    ll[k] = f2bf(v[k] - bf2f(h));
  }
  const int idx = d * 64 + ((half * 32 + tb) ^ ((d & 7) << 3));
  *(u16x8*)(Gh + idx) = hh;
  *(u16x8*)(Hl + idx) = ll;
}

// 3-term split-precision logits: acc += Ah*Bh + Ah*Bl + Al*Bh  (wave row-tile w)
static __device__ __forceinline__ void logits3(const unsigned short* Ah_, const unsigned short* Al_,
                                               const unsigned short* Bh_, const unsigned short* Bl_,
                                               int w, f32x4 acc[4]) {
  s16x8 ah[2], al[2];
#pragma unroll
  for (int ks = 0; ks < 2; ++ks) {
    ah[ks] = ld_frag(Ah_, w * 16, ks);
    al[ks] = ld_frag(Al_, w * 16, ks);
  }
#pragma unroll
  for (int ct = 0; ct < 4; ++ct) {
#pragma unroll
    for (int ks = 0; ks < 2; ++ks) {
      const s16x8 bh = ld_frag(Bh_, ct * 16, ks);
      const s16x8 bl = ld_frag(Bl_, ct * 16, ks);
      acc[ct] = MFMA(ah[ks], bh, acc[ct]);
      acc[ct] = MFMA(ah[ks], bl, acc[ct]);
      acc[ct] = MFMA(al[ks], bh, acc[ct]);
    }
  }
}

// phi = exp(logit)*sc; store row-major [t][m] swizzled LDS image.
static __device__ __forceinline__ void phi_store_row(unsigned short* dst, const f32x4* acc,
                                                     const float* sc, int w) {
  const int lane = threadIdx.x & 63;
#pragma unroll
  for (int ri = 0; ri < 4; ++ri) {
    const int t = w * 16 + ((lane & 48) >> 2) + ri;
#pragma unroll
    for (int ct = 0; ct < 4; ++ct) {
      const int m = ct * 16 + (lane & 15);
      dst[t * 64 + (m ^ ((t & 7) << 3))] = f2bf(__expf(acc[ct][ri]) * sc[ri]);
    }
  }
}

// phi stored transposed [m][t] (swizzled).
static __device__ __forceinline__ void phi_store_col(unsigned short* dst, const f32x4* acc,
                                                     const float* sc, int w) {
  const int lane = threadIdx.x & 63;
#pragma unroll
  for (int ri = 0; ri < 4; ++ri) {
    const int t = w * 16 + ((lane & 48) >> 2) + ri;
#pragma unroll
    for (int ct = 0; ct < 4; ++ct) {
      const int m = ct * 16 + (lane & 15);
      dst[m * 64 + (t ^ ((m & 7) << 3))] = f2bf(__expf(acc[ct][ri]) * sc[ri]);
    }
  }
}

// phi transposed (LDS) AND row-major linear to GLOBAL. (fallback path)
static __device__ __forceinline__ void phi_store_col_and_g(unsigned short* dstc,
                                                           unsigned short* __restrict__ gdst,
                                                           const f32x4* acc, const float* sc, int w) {
  const int lane = threadIdx.x & 63;
#pragma unroll
  for (int ri = 0; ri < 4; ++ri) {
    const int t = w * 16 + ((lane & 48) >> 2) + ri;
#pragma unroll
    for (int ct = 0; ct < 4; ++ct) {
      const int m = ct * 16 + (lane & 15);
      const unsigned short ph = f2bf(__expf(acc[ct][ri]) * sc[ri]);
      dstc[m * 64 + (t ^ ((m & 7) << 3))] = ph;
      gdst[t * 64 + m] = ph;
    }
  }
}

// ================= fused cooperative mega-kernel =================
__global__ __launch_bounds__(256, 2) void k_mega(const float* __restrict__ Qg,
                                                 const float* __restrict__ Kg,
                                                 const float* __restrict__ Vg,
                                                 const float* __restrict__ proj,
                                                 float* __restrict__ ws,
                                                 float* __restrict__ states,
                                                 float* __restrict__ tmp,
                                                 float* __restrict__ out) {
  __shared__ unsigned short A_[4096], B_[4096];  // proj hi/lo (P2; persists to P5)
  __shared__ unsigned short C_[4096], D_[4096];  // P2: K hi/lo; C_ -> phiK row image (persists); P5: D_ = Qh -> phiQ
  __shared__ unsigned short E_[4096];            // P2: phiK col; P5: Ql -> masked-A exchange
  __shared__ unsigned short G_[4096], H_[4096];  // V^T hi/lo (P2; persists to P5)
  __shared__ float F[4096];                      // P2: V f32; P5: reused as KV0/KV1 bf16 tiles
  const int tid = threadIdx.x;
  const int lane = tid & 63;
  const int w = tid >> 6;
  const int bc = blockIdx.x;
  const int b = bc >> 6;
  const int c = bc & (NCHUNK - 1);
  const int t0 = c * SS;
  const size_t tileBase = ((size_t)b * LL + t0) * DD;
  float* stc = states + ((size_t)b * NCHUNK + c) * (size_t)STATE;

  // ---------- P1: per-timestep scales; this block handles t in [bc*8, bc*8+8) ----------
  {
    const int bb = lane >> 3;
    const int d0 = (lane & 7) * 8;
#pragma unroll
    for (int s = 0; s < 2; ++s) {
      const int t = bc * 8 + w * 2 + s;
      const size_t base = (size_t)bb * (LL * DD) + (size_t)t * DD + d0;
      float sq = 0.f, sk = 0.f;
#pragma unroll
      for (int k = 0; k < 8; ++k) {
        const float q = Qg[base + k]; sq += q * q;
        const float kk = Kg[base + k]; sk += kk * kk;
      }
#pragma unroll
      for (int off = 32; off; off >>= 1) {
        sq += __shfl_xor(sq, off);
        sk += __shfl_xor(sk, off);
      }
      if (lane == 0) {
        ws[t]      = expf(-0.5f * sqrtf(sq));
        ws[LL + t] = expf(-0.5f * sqrtf(sk));
      }
    }
  }
  cg::this_grid().sync();

  // ---------- P2: phiK + chunk sums ----------
  stage_hl(A_, B_, proj, tid);
  stage_hl(C_, D_, Kg + tileBase, tid);
  stage_vfull(F, Vg + tileBase, tid);
  {
    float sck[4];
#pragma unroll
    for (int ri = 0; ri < 4; ++ri) {
      const int trow = w * 16 + ((lane & 48) >> 2) + ri;
      sck[ri] = ws[LL + t0 + trow] * 0.125f;  // * 1/sqrt(64)
    }
    __syncthreads();  // bar0: staged

    f32x4 acc[4] = {};
    logits3(C_, D_, A_, B_, w, acc);
    phi_store_row(C_, acc, sck, w);  // phiK row image (in place over Kh; persists to P5)
    phi_store_col(E_, acc, sck, w);  // phiK col image
  }
  vtrans_half(G_, H_, F, tid, 0);
  vtrans_half(G_, H_, F + 32 * 64, tid, 1);
  __syncthreads();  // bar1: E_, G_, H_ complete

  {  // N[m] = colsum of quantized phiK
    const int m = tid >> 2, q = tid & 3;
    float s = 0.f;
#pragma unroll
    for (int p = 0; p < 2; ++p) {
      const int tt = q * 16 + p * 8;
      const u16x8 vv = *(const u16x8*)(E_ + m * 64 + (tt ^ ((m & 7) << 3)));
#pragma unroll
      for (int i = 0; i < 8; ++i) s += bf2f(vv[i]);
    }
    s += __shfl_xor(s, 1);
    s += __shfl_xor(s, 2);
    if (q == 0) stc[4096 + m] = s;
  }
  {  // KVT[d][m] = sum_t VT[d][t] * phiK[t][m]  (V hi/lo)
    s16x8 avh[2], avl[2];
#pragma unroll
    for (int ks = 0; ks < 2; ++ks) {
      avh[ks] = ld_frag(G_, w * 16, ks);
      avl[ks] = ld_frag(H_, w * 16, ks);
    }
    f32x4 acc[4] = {};
#pragma unroll
    for (int ct = 0; ct < 4; ++ct)
#pragma unroll
      for (int ks = 0; ks < 2; ++ks) {
        const s16x8 bp = ld_frag(E_, ct * 16, ks);
        acc[ct] = MFMA(avh[ks], bp, acc[ct]);
        acc[ct] = MFMA(avl[ks], bp, acc[ct]);
      }
#pragma unroll
    for (int ri = 0; ri < 4; ++ri) {
      const int d = w * 16 + ((lane & 48) >> 2) + ri;
#pragma unroll
      for (int ct = 0; ct < 4; ++ct) {
        stc[d * 64 + ct * 16 + (lane & 15)] = acc[ct][ri];
      }
    }
  }
  cg::this_grid().sync();

  // ---------- P3: prefix pass 1 (grid-stride) ----------
  for (int e = bc * 256 + tid; e < BB * 8 * STATE; e += 512 * 256) {
    const int b1 = e / (8 * STATE);
    const int r = e % (8 * STATE);
    const int g = r / STATE;
    const int el = r % STATE;
    const float* p = states + ((size_t)b1 * NCHUNK + g * 8) * STATE + el;
    float s = 0.f;
#pragma unroll
    for (int i = 0; i < 8; ++i) s += p[(size_t)i * STATE];
    tmp[((size_t)b1 * 8 + g) * STATE + el] = s;
  }
  cg::this_grid().sync();

  // ---------- P4: prefix pass 2 (grid-stride) ----------
  for (int e = bc * 256 + tid; e < BB * 8 * STATE; e += 512 * 256) {
    const int b1 = e / (8 * STATE);
    const int r = e % (8 * STATE);
    const int g = r / STATE;
    const int el = r % STATE;
    float run = 0.f;
    for (int g2 = 0; g2 < g; ++g2) run += tmp[((size_t)b1 * 8 + g2) * STATE + el];
    float* p = states + ((size_t)b1 * NCHUNK + g * 8) * STATE + el;
#pragma unroll
    for (int i = 0; i < 8; ++i) {
      const float v = p[(size_t)i * STATE];
      p[(size_t)i * STATE] = run;
      run += v;
    }
  }
  cg::this_grid().sync();

  // ---------- P5: outputs (proj/phiK/VT still live in LDS; 1 barrier) ----------
  {
    unsigned short* KV0 = (unsigned short*)F;
    unsigned short* KV1 = KV0 + 4096;
    stage_hl(D_, E_, Qg + tileBase, tid);  // Q hi/lo over dead Kh-copy/phiK-col
    stage_hl(KV0, KV1, stc, tid);          // exclusive-prefix KV hi/lo
    float scq[4];
#pragma unroll
    for (int ri = 0; ri < 4; ++ri) {
      const int trow = w * 16 + ((lane & 48) >> 2) + ri;
      scq[ri] = ws[t0 + trow] * 0.125f;
    }
    __syncthreads();  // bar2: Q + KV staged

    // phiQ -> D_ in place; A-frags
    s16x8 aq[2];
    {
      f32x4 acc[4] = {};
      logits3(D_, E_, A_, B_, w, acc);
      phi_store_row(D_, acc, scq, w);
#pragma unroll
      for (int ks = 0; ks < 2; ++ks) aq[ks] = ld_frag(D_, w * 16, ks);
    }

    // A = phiQ . phiK^T (phiK row image = C_), masked + quantized -> E_ (wave-local rows)
    float rsI[4];
    {
      f32x4 accA[4] = {};
#pragma unroll
      for (int ct = 0; ct < 4; ++ct)
#pragma unroll
        for (int ks = 0; ks < 2; ++ks)
          accA[ct] = MFMA(aq[ks], ld_frag(C_, ct * 16, ks), accA[ct]);
#pragma unroll
      for (int ri = 0; ri < 4; ++ri) {
        const int t = w * 16 + ((lane & 48) >> 2) + ri;
        float part = 0.f;
#pragma unroll
        for (int ct = 0; ct < 4; ++ct) {
          const int j = ct * 16 + (lane & 15);
          const float a = (j <= t) ? accA[ct][ri] : 0.f;
          const unsigned short ah = f2bf(a);
          part += bf2f(ah);
          E_[t * 64 + (j ^ ((t & 7) << 3))] = ah;
        }
#pragma unroll
        for (int off = 1; off < 16; off <<= 1) part += __shfl_xor(part, off);
        rsI[ri] = part;
      }
    }
    // no barrier: all cross-wave operands (A_,B_,C_,G_,H_,KV) are stable; D_/E_ rows are wave-local

    // acc = A.(VTh+VTl)^T + phiQ.(KVh+KVl);  r = rsI + phiQ.Npref
    {
      s16x8 aA[2];
#pragma unroll
      for (int ks = 0; ks < 2; ++ks) aA[ks] = ld_frag(E_, w * 16, ks);
      f32x4 acc[4] = {};
#pragma unroll
      for (int ct = 0; ct < 4; ++ct) {
#pragma unroll
        for (int ks = 0; ks < 2; ++ks) {
          acc[ct] = MFMA(aA[ks], ld_frag(G_, ct * 16, ks), acc[ct]);
          acc[ct] = MFMA(aA[ks], ld_frag(H_, ct * 16, ks), acc[ct]);
          acc[ct] = MFMA(aq[ks], ld_frag(KV0, ct * 16, ks), acc[ct]);
          acc[ct] = MFMA(aq[ks], ld_frag(KV1, ct * 16, ks), acc[ct]);
        }
      }
      float rsp = 0.f;
      const float* Np = stc + 4096;
#pragma unroll
      for (int ks = 0; ks < 2; ++ks) {
        const int m0 = ks * 32 + ((lane & 48) >> 1);
        const float4 n0 = *(const float4*)(Np + m0);
        const float4 n1 = *(const float4*)(Np + m0 + 4);
        const float nn[8] = {n0.x, n0.y, n0.z, n0.w, n1.x, n1.y, n1.z, n1.w};
#pragma unroll
        for (int i = 0; i < 8; ++i) rsp += bf2f((unsigned short)aq[ks][i]) * nn[i];
      }
      rsp += __shfl_xor(rsp, 16);
      rsp += __shfl_xor(rsp, 32);
#pragma unroll
      for (int ri = 0; ri < 4; ++ri) {
        const float r = rsI[ri] + __shfl(rsp, ((lane & 48) >> 2) + ri);
        const float inv = 1.f / (r + copysignf(1e-6f, r));
        const int t = w * 16 + ((lane & 48) >> 2) + ri;
#pragma unroll
        for (int ct = 0; ct < 4; ++ct) {
          out[tileBase + t * 64 + ct * 16 + (lane & 15)] = acc[ct][ri] * inv;
        }
      }
    }
  }
}

// ================= fallback path (R8, proven 34.5 us) =================
__global__ __launch_bounds__(256) void k_scales(const float* __restrict__ Q,
                                                const float* __restrict__ K,
                                                float* __restrict__ ws) {
  const int t = blockIdx.x * 4 + (threadIdx.x >> 6);
  const int lane = threadIdx.x & 63;
  const int b = lane >> 3;
  const int d0 = (lane & 7) * 8;
  const size_t base = (size_t)b * (LL * DD) + (size_t)t * DD + d0;
  float sq = 0.f, sk = 0.f;
#pragma unroll
  for (int k = 0; k < 8; ++k) {
    const float q = Q[base + k]; sq += q * q;
    const float kk = K[base + k]; sk += kk * kk;
  }
#pragma unroll
  for (int off = 32; off; off >>= 1) {
    sq += __shfl_xor(sq, off);
    sk += __shfl_xor(sk, off);
  }
  if (lane == 0) {
    ws[t]      = expf(-0.5f * sqrtf(sq));
    ws[LL + t] = expf(-0.5f * sqrtf(sk));
  }
}

__global__ __launch_bounds__(256) void k_chunk_sums(const float* __restrict__ Kg,
                                                    const float* __restrict__ Vg,
                                                    const float* __restrict__ proj,
                                                    const float* __restrict__ ws,
                                                    float* __restrict__ states,
                                                    unsigned short* __restrict__ phiKg) {
  __shared__ unsigned short A_[4096], B_[4096];
  __shared__ unsigned short C_[4096], D_[4096];
  __shared__ unsigned short E_[4096];
  __shared__ unsigned short G_[4096], H_[4096];
  __shared__ float F[4096];
  const int tid = threadIdx.x;
  const int lane = tid & 63;
  const int w = tid >> 6;
  const int bc = blockIdx.x;
  const int b = bc >> 6;
  const int c = bc & (NCHUNK - 1);
  const int t0 = c * SS;
  const size_t tileBase = ((size_t)b * LL + t0) * DD;
  float* stc = states + ((size_t)b * NCHUNK + c) * (size_t)STATE;
  unsigned short* pkT = phiKg + (size_t)bc * 4096;

  stage_hl(A_, B_, proj, tid);
  stage_hl(C_, D_, Kg + tileBase, tid);
  stage_vfull(F, Vg + tileBase, tid);
  float sck[4];
#pragma unroll
  for (int ri = 0; ri < 4; ++ri) {
    const int trow = w * 16 + ((lane & 48) >> 2) + ri;
    sck[ri] = ws[LL + t0 + trow] * 0.125f;
  }
  __syncthreads();

  {
    f32x4 acc[4] = {};
    logits3(C_, D_, A_, B_, w, acc);
    phi_store_col_and_g(E_, pkT, acc, sck, w);
  }
  vtrans_half(G_, H_, F, tid, 0);
  vtrans_half(G_, H_, F + 32 * 64, tid, 1);
  __syncthreads();

  {
    const int m = tid >> 2, q = tid & 3;
    float s = 0.f;
#pragma unroll
    for (int p = 0; p < 2; ++p) {
      const int tt = q * 16 + p * 8;
      const u16x8 vv = *(const u16x8*)(E_ + m * 64 + (tt ^ ((m & 7) << 3)));
#pragma unroll
      for (int i = 0; i < 8; ++i) s += bf2f(vv[i]);
    }
    s += __shfl_xor(s, 1);
    s += __shfl_xor(s, 2);
    if (q == 0) stc[4096 + m] = s;
  }
  {
    s16x8 avh[2], avl[2];
#pragma unroll
    for (int ks = 0; ks < 2; ++ks) {
      avh[ks] = ld_frag(G_, w * 16, ks);
      avl[ks] = ld_frag(H_, w * 16, ks);
    }
    f32x4 acc[4] = {};
#pragma unroll
    for (int ct = 0; ct < 4; ++ct)
#pragma unroll
      for (int ks = 0; ks < 2; ++ks) {
        const s16x8 bp = ld_frag(E_, ct * 16, ks);
        acc[ct] = MFMA(avh[ks], bp, acc[ct]);
        acc[ct] = MFMA(avl[ks], bp, acc[ct]);
      }
#pragma unroll
    for (int ri = 0; ri < 4; ++ri) {
      const int d = w * 16 + ((lane & 48) >> 2) + ri;
#pragma unroll
      for (int ct = 0; ct < 4; ++ct) {
        stc[d * 64 + ct * 16 + (lane & 15)] = acc[ct][ri];
      }
    }
  }
}

__global__ __launch_bounds__(256) void k_prefix1(const float* __restrict__ states,
                                                 float* __restrict__ tmp) {
  const int e = blockIdx.x * 256 + threadIdx.x;
  if (e >= BB * 8 * STATE) return;
  const int b = e / (8 * STATE);
  const int r = e % (8 * STATE);
  const int g = r / STATE;
  const int el = r % STATE;
  const float* p = states + ((size_t)b * NCHUNK + g * 8) * STATE + el;
  float s = 0.f;
#pragma unroll
  for (int i = 0; i < 8; ++i) s += p[(size_t)i * STATE];
  tmp[((size_t)b * 8 + g) * STATE + el] = s;
}

__global__ __launch_bounds__(256) void k_prefix2(float* __restrict__ states,
                                                 const float* __restrict__ tmp) {
  const int e = blockIdx.x * 256 + threadIdx.x;
  if (e >= BB * 8 * STATE) return;
  const int b = e / (8 * STATE);
  const int r = e % (8 * STATE);
  const int g = r / STATE;
  const int el = r % STATE;
  float run = 0.f;
  for (int g2 = 0; g2 < g; ++g2) run += tmp[((size_t)b * 8 + g2) * STATE + el];
  float* p = states + ((size_t)b * NCHUNK + g * 8) * STATE + el;
#pragma unroll
  for (int i = 0; i < 8; ++i) {
    const float v = p[(size_t)i * STATE];
    p[(size_t)i * STATE] = run;
    run += v;
  }
}

__global__ __launch_bounds__(256) void k_out(const float* __restrict__ Qg,
                                             const float* __restrict__ Vg,
                                             const float* __restrict__ proj,
                                             const unsigned short* __restrict__ phiKg,
                                             const float* __restrict__ ws,
                                             const float* __restrict__ states,
                                             float* __restrict__ out) {
  __shared__ unsigned short A_[4096], B_[4096];
  __shared__ unsigned short C_[4096];
  __shared__ unsigned short D_[4096];
  __shared__ unsigned short PK[4096];
  __shared__ unsigned short KV0[4096], KV1[4096];
  __shared__ float F[4096];
  const int tid = threadIdx.x;
  const int lane = tid & 63;
  const int w = tid >> 6;
  const int bc = blockIdx.x;
  const int b = bc >> 6;
  const int c = bc & (NCHUNK - 1);
  const int t0 = c * SS;
  const size_t tileBase = ((size_t)b * LL + t0) * DD;
  const float* st = states + ((size_t)b * NCHUNK + c) * (size_t)STATE;
  const unsigned short* pkT = phiKg + (size_t)bc * 4096;

  stage_hl(A_, B_, proj, tid);
  stage_hl(C_, D_, Qg + tileBase, tid);
  stage_img(PK, pkT, tid);
  stage_hl(KV0, KV1, st, tid);
  stage_vfull(F, Vg + tileBase, tid);
  float scq[4];
#pragma unroll
  for (int ri = 0; ri < 4; ++ri) {
    const int trow = w * 16 + ((lane & 48) >> 2) + ri;
    scq[ri] = ws[t0 + trow] * 0.125f;
  }
  __syncthreads();

  s16x8 aq[2];
  {
    f32x4 acc[4] = {};
    logits3(C_, D_, A_, B_, w, acc);
    phi_store_row(C_, acc, scq, w);
#pragma unroll
    for (int ks = 0; ks < 2; ++ks) aq[ks] = ld_frag(C_, w * 16, ks);
  }
  __syncthreads();

  vtrans_half(A_, B_, F, tid, 0);
  vtrans_half(A_, B_, F + 32 * 64, tid, 1);

  float rsI[4];
  {
    f32x4 accA[4] = {};
#pragma unroll
    for (int ct = 0; ct < 4; ++ct)
#pragma unroll
      for (int ks = 0; ks < 2; ++ks)
        accA[ct] = MFMA(aq[ks], ld_frag(PK, ct * 16, ks), accA[ct]);
#pragma unroll
    for (int ri = 0; ri < 4; ++ri) {
      const int t = w * 16 + ((lane & 48) >> 2) + ri;
      float part = 0.f;
#pragma unroll
      for (int ct = 0; ct < 4; ++ct) {
        const int j = ct * 16 + (lane & 15);
        const float a = (j <= t) ? accA[ct][ri] : 0.f;
        const unsigned short ah = f2bf(a);
        part += bf2f(ah);
        D_[t * 64 + (j ^ ((t & 7) << 3))] = ah;
      }
#pragma unroll
      for (int off = 1; off < 16; off <<= 1) part += __shfl_xor(part, off);
      rsI[ri] = part;
    }
  }
  __syncthreads();

  {
    s16x8 aA[2];
#pragma unroll
    for (int ks = 0; ks < 2; ++ks) aA[ks] = ld_frag(D_, w * 16, ks);
    f32x4 acc[4] = {};
#pragma unroll
    for (int ct = 0; ct < 4; ++ct) {
#pragma unroll
      for (int ks = 0; ks < 2; ++ks) {
        acc[ct] = MFMA(aA[ks], ld_frag(A_, ct * 16, ks), acc[ct]);
        acc[ct] = MFMA(aA[ks], ld_frag(B_, ct * 16, ks), acc[ct]);
        acc[ct] = MFMA(aq[ks], ld_frag(KV0, ct * 16, ks), acc[ct]);
        acc[ct] = MFMA(aq[ks], ld_frag(KV1, ct * 16, ks), acc[ct]);
      }
    }
    float rsp = 0.f;
    const float* Np = st + 4096;
#pragma unroll
    for (int ks = 0; ks < 2; ++ks) {
      const int m0 = ks * 32 + ((lane & 48) >> 1);
      const float4 n0 = *(const float4*)(Np + m0);
      const float4 n1 = *(const float4*)(Np + m0 + 4);
      const float nn[8] = {n0.x, n0.y, n0.z, n0.w, n1.x, n1.y, n1.z, n1.w};
#pragma unroll
      for (int i = 0; i < 8; ++i) rsp += bf2f((unsigned short)aq[ks][i]) * nn[i];
    }
    rsp += __shfl_xor(rsp, 16);
    rsp += __shfl_xor(rsp, 32);
#pragma unroll
    for (int ri = 0; ri < 4; ++ri) {
      const float r = rsI[ri] + __shfl(rsp, ((lane & 48) >> 2) + ri);
      const float inv = 1.f / (r + copysignf(1e-6f, r));
      const int t = w * 16 + ((lane & 48) >> 2) + ri;
#pragma unroll
      for (int ct = 0; ct < 4; ++ct) {
        out[tileBase + t * 64 + ct * 16 + (lane & 15)] = acc[ct][ri] * inv;
      }
    }
  }
}

extern "C" void kernel_launch(void* const* d_in, const int* in_sizes, int n_in,
                              void* d_out, int out_size, void* d_ws, size_t ws_size,
                              hipStream_t stream) {
  (void)in_sizes; (void)n_in; (void)out_size; (void)ws_size;
  const float* Q    = (const float*)d_in[0];
  const float* K    = (const float*)d_in[1];
  const float* V    = (const float*)d_in[2];
  const float* proj = (const float*)d_in[4];  // d_in[3] = sent_embed_slice (unused)
  float* out = (float*)d_out;
  float* ws  = (float*)d_ws;                  // [0,L): scaleQ, [L,2L): scaleK
  float* states = ws + 2 * LL;                // B*64*4160 f
  const size_t statesFloats = (size_t)BB * NCHUNK * STATE;
  float* tmp = states + statesFloats;         // B*8*4160 f
  const size_t tmpFloats = (size_t)BB * 8 * STATE;
  unsigned short* phiKg = (unsigned short*)(tmp + tmpFloats);  // fallback only

  void* args[] = {(void*)&Q, (void*)&K, (void*)&V, (void*)&proj,
                  (void*)&ws, (void*)&states, (void*)&tmp, (void*)&out};
  hipError_t err = hipLaunchCooperativeKernel((const void*)k_mega, dim3(BB * NCHUNK), dim3(256),
                                              args, 0, stream);
  if (err != hipSuccess) {
    // fallback: proven 5-kernel path
    hipLaunchKernelGGL(k_scales, dim3(LL / 4), dim3(256), 0, stream, Q, K, ws);
    hipLaunchKernelGGL(k_chunk_sums, dim3(BB * NCHUNK), dim3(256), 0, stream,
                       K, V, proj, ws, states, phiKg);
    hipLaunchKernelGGL(k_prefix1, dim3((BB * 8 * STATE + 255) / 256), dim3(256), 0, stream, states, tmp);
    hipLaunchKernelGGL(k_prefix2, dim3((BB * 8 * STATE + 255) / 256), dim3(256), 0, stream, states, tmp);
    hipLaunchKernelGGL(k_out, dim3(BB * NCHUNK), dim3(256), 0, stream,
                       Q, V, proj, phiKg, ws, states, out);
  }
}

// Round 10
// 38.624 us; speedup vs baseline: 6.6560x; 6.6560x over previous
//
#include <hip/hip_runtime.h>
#include <math.h>

// B=8, L=4096, D=64, M=64, masked=1 (fixed by setup_inputs)
#define BB 8
#define LL 4096
#define DD 64
#define SS 64
#define NCHUNK 64
#define STATE 4160  // 64x64 KV^T rows (d-major) + 64 N values

typedef __attribute__((ext_vector_type(8))) short s16x8;
typedef __attribute__((ext_vector_type(8))) unsigned short u16x8;
typedef __attribute__((ext_vector_type(4))) float f32x4;

#define MFMA(a, b, c) __builtin_amdgcn_mfma_f32_16x16x32_bf16((a), (b), (c), 0, 0, 0)

static __device__ __forceinline__ unsigned short f2bf(float x) {
  unsigned int u = __builtin_bit_cast(unsigned int, x);
  u += 0x7FFFu + ((u >> 16) & 1u);
  return (unsigned short)(u >> 16);
}
static __device__ __forceinline__ float bf2f(unsigned short h) {
  unsigned int u = ((unsigned int)h) << 16;
  return __builtin_bit_cast(float, u);
}

// LDS bf16 tile, row-major 64 cols, XOR-swizzled: elem (r,k) at r*64 + (k ^ ((r&7)<<3)).
// Frag: row r = row0 + (lane&15), k = ks*32 + (lane>>4)*8 .. +8.
static __device__ __forceinline__ s16x8 ld_frag(const unsigned short* base, int row0, int ks) {
  const int lane = threadIdx.x & 63;
  const int r = row0 + (lane & 15);
  const int idx = r * 64 + ((ks * 32 + ((lane & 48) >> 1)) ^ ((r & 7) << 3));
  return *(const s16x8*)(base + idx);
}

// Stage a 64x64 f32 global tile into hi/lo bf16 LDS tiles (swizzled). Coalesced.
static __device__ __forceinline__ void stage_hl(unsigned short* __restrict__ Sh,
                                                unsigned short* __restrict__ Sl,
                                                const float* __restrict__ src, int tid) {
#pragma unroll
  for (int it = 0; it < 2; ++it) {
    const int g = tid + it * 256;
    const int row = g >> 3;
    const int c0 = (g & 7) * 8;
    const float4 x0 = *(const float4*)(src + row * 64 + c0);
    const float4 x1 = *(const float4*)(src + row * 64 + c0 + 4);
    const float xs[8] = {x0.x, x0.y, x0.z, x0.w, x1.x, x1.y, x1.z, x1.w};
    u16x8 h, l;
#pragma unroll
    for (int k = 0; k < 8; ++k) {
      const unsigned short hh = f2bf(xs[k]);
      h[k] = hh;
      l[k] = f2bf(xs[k] - bf2f(hh));
    }
    const int idx = row * 64 + (c0 ^ ((row & 7) << 3));
    *(u16x8*)(Sh + idx) = h;
    *(u16x8*)(Sl + idx) = l;
  }
}

// Stage full 64x64 V f32 tile (coalesced).
static __device__ __forceinline__ void stage_vfull(float* __restrict__ F, const float* __restrict__ src,
                                                   int tid) {
#pragma unroll
  for (int it = 0; it < 4; ++it) {
    const int g = tid + it * 256;
    const int row = g >> 4;
    const int col = (g & 15) * 4;
    *(float4*)(F + row * 64 + col) = *(const float4*)(src + row * 64 + col);
  }
}

// Stage a linear bf16 [64][64] global image into a swizzled LDS tile. Coalesced.
static __device__ __forceinline__ void stage_img(unsigned short* __restrict__ S,
                                                 const unsigned short* __restrict__ src, int tid) {
#pragma unroll
  for (int it = 0; it < 2; ++it) {
    const int g = tid + it * 256;
    const int row = g >> 3;
    const int c0 = (g & 7) * 8;
    *(u16x8*)(S + row * 64 + (c0 ^ ((row & 7) << 3))) = *(const u16x8*)(src + row * 64 + c0);
  }
}

// Transpose 32 rows of f32 scratch into VT hi/lo bf16 tiles: VT[d][t] (swizzled).
static __device__ __forceinline__ void vtrans_half(unsigned short* __restrict__ Gh,
                                                   unsigned short* __restrict__ Hl,
                                                   const float* __restrict__ F, int tid, int half) {
  const int d = tid & 63;
  const int tb = (tid >> 6) * 8;
  float v[8];
#pragma unroll
  for (int k = 0; k < 8; ++k) v[k] = F[(tb + k) * 64 + d];
  u16x8 hh, ll;
#pragma unroll
  for (int k = 0; k < 8; ++k) {
    const unsigned short h = f2bf(v[k]);
    hh[k] = h;
    ll[k] = f2bf(v[k] - bf2f(h));
  }
  const int idx = d * 64 + ((half * 32 + tb) ^ ((d & 7) << 3));
  *(u16x8*)(Gh + idx) = hh;
  *(u16x8*)(Hl + idx) = ll;
}

// 3-term split-precision logits: acc += Ah*Bh + Ah*Bl + Al*Bh  (wave row-tile w)
static __device__ __forceinline__ void logits3(const unsigned short* Ah_, const unsigned short* Al_,
                                               const unsigned short* Bh_, const unsigned short* Bl_,
                                               int w, f32x4 acc[4]) {
  s16x8 ah[2], al[2];
#pragma unroll
  for (int ks = 0; ks < 2; ++ks) {
    ah[ks] = ld_frag(Ah_, w * 16, ks);
    al[ks] = ld_frag(Al_, w * 16, ks);
  }
#pragma unroll
  for (int ct = 0; ct < 4; ++ct) {
#pragma unroll
    for (int ks = 0; ks < 2; ++ks) {
      const s16x8 bh = ld_frag(Bh_, ct * 16, ks);
      const s16x8 bl = ld_frag(Bl_, ct * 16, ks);
      acc[ct] = MFMA(ah[ks], bh, acc[ct]);
      acc[ct] = MFMA(ah[ks], bl, acc[ct]);
      acc[ct] = MFMA(al[ks], bh, acc[ct]);
    }
  }
}

// phi = exp(logit)*sc; store row-major [t][m] swizzled LDS image.
static __device__ __forceinline__ void phi_store_row(unsigned short* dst, const f32x4* acc,
                                                     const float* sc, int w) {
  const int lane = threadIdx.x & 63;
#pragma unroll
  for (int ri = 0; ri < 4; ++ri) {
    const int t = w * 16 + ((lane & 48) >> 2) + ri;
#pragma unroll
    for (int ct = 0; ct < 4; ++ct) {
      const int m = ct * 16 + (lane & 15);
      dst[t * 64 + (m ^ ((t & 7) << 3))] = f2bf(__expf(acc[ct][ri]) * sc[ri]);
    }
  }
}

// phi transposed (swizzled LDS) AND row-major linear to GLOBAL [t][m].
static __device__ __forceinline__ void phi_store_col_and_g(unsigned short* dstc,
                                                           unsigned short* __restrict__ gdst,
                                                           const f32x4* acc, const float* sc, int w) {
  const int lane = threadIdx.x & 63;
#pragma unroll
  for (int ri = 0; ri < 4; ++ri) {
    const int t = w * 16 + ((lane & 48) >> 2) + ri;
#pragma unroll
    for (int ct = 0; ct < 4; ++ct) {
      const int m = ct * 16 + (lane & 15);
      const unsigned short ph = f2bf(__expf(acc[ct][ri]) * sc[ri]);
      dstc[m * 64 + (t ^ ((m & 7) << 3))] = ph;
      gdst[t * 64 + m] = ph;
    }
  }
}

// ---------------- K1: per-timestep scales (vectorized) ----------------
__global__ __launch_bounds__(256) void k_scales(const float* __restrict__ Q,
                                                const float* __restrict__ K,
                                                float* __restrict__ ws) {
  const int t = blockIdx.x * 4 + (threadIdx.x >> 6);
  const int lane = threadIdx.x & 63;
  const int b = lane >> 3;
  const int d0 = (lane & 7) * 8;
  const size_t base = (size_t)b * (LL * DD) + (size_t)t * DD + d0;
  const float4 q0 = *(const float4*)(Q + base);
  const float4 q1 = *(const float4*)(Q + base + 4);
  const float4 k0 = *(const float4*)(K + base);
  const float4 k1 = *(const float4*)(K + base + 4);
  float sq = q0.x * q0.x + q0.y * q0.y + q0.z * q0.z + q0.w * q0.w +
             q1.x * q1.x + q1.y * q1.y + q1.z * q1.z + q1.w * q1.w;
  float sk = k0.x * k0.x + k0.y * k0.y + k0.z * k0.z + k0.w * k0.w +
             k1.x * k1.x + k1.y * k1.y + k1.z * k1.z + k1.w * k1.w;
#pragma unroll
  for (int off = 32; off; off >>= 1) {
    sq += __shfl_xor(sq, off);
    sk += __shfl_xor(sk, off);
  }
  if (lane == 0) {
    ws[t]      = expf(-0.5f * sqrtf(sq));
    ws[LL + t] = expf(-0.5f * sqrtf(sk));
  }
}

// ---------------- K2: phiK + per-chunk sums (unchanged from R8) ----------------
__global__ __launch_bounds__(256) void k_chunk_sums(const float* __restrict__ Kg,
                                                    const float* __restrict__ Vg,
                                                    const float* __restrict__ proj,
                                                    const float* __restrict__ ws,
                                                    float* __restrict__ states,
                                                    unsigned short* __restrict__ phiKg) {
  __shared__ unsigned short A_[4096], B_[4096];  // proj hi/lo
  __shared__ unsigned short C_[4096], D_[4096];  // K hi/lo
  __shared__ unsigned short E_[4096];            // phiK col [m][t] (swz)
  __shared__ unsigned short G_[4096], H_[4096];  // V^T hi/lo [d][t] (swz)
  __shared__ float F[4096];                      // V full f32
  const int tid = threadIdx.x;
  const int lane = tid & 63;
  const int w = tid >> 6;
  const int bc = blockIdx.x;
  const int b = bc >> 6;
  const int c = bc & (NCHUNK - 1);
  const int t0 = c * SS;
  const size_t tileBase = ((size_t)b * LL + t0) * DD;
  float* stc = states + ((size_t)b * NCHUNK + c) * (size_t)STATE;
  unsigned short* pkT = phiKg + (size_t)bc * 4096;

  stage_hl(A_, B_, proj, tid);
  stage_hl(C_, D_, Kg + tileBase, tid);
  stage_vfull(F, Vg + tileBase, tid);
  float sck[4];
#pragma unroll
  for (int ri = 0; ri < 4; ++ri) {
    const int trow = w * 16 + ((lane & 48) >> 2) + ri;
    sck[ri] = ws[LL + t0 + trow] * 0.125f;  // * 1/sqrt(64)
  }
  __syncthreads();  // bar0: all staged

  {  // phiK logits -> col image (LDS) + row image (global, for k_out)
    f32x4 acc[4] = {};
    logits3(C_, D_, A_, B_, w, acc);
    phi_store_col_and_g(E_, pkT, acc, sck, w);
  }
  vtrans_half(G_, H_, F, tid, 0);
  vtrans_half(G_, H_, F + 32 * 64, tid, 1);
  __syncthreads();  // bar1: E_, G_, H_ complete

  {  // N[m] = colsum of quantized phiK
    const int m = tid >> 2, q = tid & 3;
    float s = 0.f;
#pragma unroll
    for (int p = 0; p < 2; ++p) {
      const int tt = q * 16 + p * 8;
      const u16x8 vv = *(const u16x8*)(E_ + m * 64 + (tt ^ ((m & 7) << 3)));
#pragma unroll
      for (int i = 0; i < 8; ++i) s += bf2f(vv[i]);
    }
    s += __shfl_xor(s, 1);
    s += __shfl_xor(s, 2);
    if (q == 0) stc[4096 + m] = s;
  }
  {  // KVT[d][m] = sum_t VT[d][t] * phiK[t][m]  (V hi/lo)
    s16x8 avh[2], avl[2];
#pragma unroll
    for (int ks = 0; ks < 2; ++ks) {
      avh[ks] = ld_frag(G_, w * 16, ks);
      avl[ks] = ld_frag(H_, w * 16, ks);
    }
    f32x4 acc[4] = {};
#pragma unroll
    for (int ct = 0; ct < 4; ++ct)
#pragma unroll
      for (int ks = 0; ks < 2; ++ks) {
        const s16x8 bp = ld_frag(E_, ct * 16, ks);
        acc[ct] = MFMA(avh[ks], bp, acc[ct]);
        acc[ct] = MFMA(avl[ks], bp, acc[ct]);
      }
#pragma unroll
    for (int ri = 0; ri < 4; ++ri) {
      const int d = w * 16 + ((lane & 48) >> 2) + ri;
#pragma unroll
      for (int ct = 0; ct < 4; ++ct) {
        stc[d * 64 + ct * 16 + (lane & 15)] = acc[ct][ri];
      }
    }
  }
}

// ---------------- K3: exclusive GROUP prefix only (replaces prefix1+prefix2) ----------------
// tmp[b][g][el] = sum over chunks < 8g (same accumulation order as the old 2-pass).
__global__ __launch_bounds__(256) void k_groups(const float* __restrict__ states,
                                                float* __restrict__ tmp) {
  const int e = blockIdx.x * 256 + threadIdx.x;
  if (e >= BB * STATE) return;
  const int b = e / STATE;
  const int el = e % STATE;
  const float* p = states + (size_t)b * NCHUNK * STATE + el;
  float run = 0.f;
#pragma unroll
  for (int g = 0; g < 8; ++g) {
    tmp[((size_t)b * 8 + g) * STATE + el] = run;
    float s = 0.f;
#pragma unroll
    for (int i = 0; i < 8; ++i) s += p[(size_t)(g * 8 + i) * STATE];
    run += s;
  }
}

// ---------------- K4: outputs; finishes the chunk prefix inline during staging ----------------
__global__ __launch_bounds__(256) void k_out(const float* __restrict__ Qg,
                                             const float* __restrict__ Vg,
                                             const float* __restrict__ proj,
                                             const unsigned short* __restrict__ phiKg,
                                             const float* __restrict__ ws,
                                             const float* __restrict__ states,
                                             const float* __restrict__ tmp,
                                             float* __restrict__ out) {
  __shared__ unsigned short A_[4096], B_[4096];  // proj hi/lo -> VT hi/lo
  __shared__ unsigned short C_[4096];            // Qh -> phiQ image [t][m]
  __shared__ unsigned short D_[4096];            // Ql -> E (masked quantized A)
  __shared__ unsigned short PK[4096];            // phiK image [j][m] (swz)
  __shared__ unsigned short KV0[4096], KV1[4096];// KV prefix hi/lo [d][m]
  __shared__ float F[4096];                      // V f32 full tile
  __shared__ float NP[64];                       // N prefix (f32)
  const int tid = threadIdx.x;
  const int lane = tid & 63;
  const int w = tid >> 6;
  const int bc = blockIdx.x;
  const int b = bc >> 6;
  const int c = bc & (NCHUNK - 1);
  const int g = c >> 3;
  const int t0 = c * SS;
  const size_t tileBase = ((size_t)b * LL + t0) * DD;
  const float* tgp = tmp + ((size_t)b * 8 + g) * STATE;            // exclusive group prefix
  const float* stb = states + (size_t)b * NCHUNK * STATE;          // batch states base
  const unsigned short* pkT = phiKg + (size_t)bc * 4096;
  const int ccnt = c - g * 8;                                       // chunks to add within group

  stage_hl(A_, B_, proj, tid);
  stage_hl(C_, D_, Qg + tileBase, tid);
  stage_img(PK, pkT, tid);
  stage_vfull(F, Vg + tileBase, tid);

  // KV prefix: tgp + sum of states[8g .. c) accumulated in registers (order == old prefix2),
  // then quantize hi/lo into KV0/KV1.
#pragma unroll
  for (int it = 0; it < 2; ++it) {
    const int gg = tid + it * 256;
    const int row = gg >> 3;
    const int c0 = (gg & 7) * 8;
    const int off = row * 64 + c0;
    float4 a0 = *(const float4*)(tgp + off);
    float4 a1 = *(const float4*)(tgp + off + 4);
    for (int cc = 0; cc < ccnt; ++cc) {
      const float* sp = stb + (size_t)(g * 8 + cc) * STATE + off;
      const float4 s0 = *(const float4*)(sp);
      const float4 s1 = *(const float4*)(sp + 4);
      a0.x += s0.x; a0.y += s0.y; a0.z += s0.z; a0.w += s0.w;
      a1.x += s1.x; a1.y += s1.y; a1.z += s1.z; a1.w += s1.w;
    }
    const float xs[8] = {a0.x, a0.y, a0.z, a0.w, a1.x, a1.y, a1.z, a1.w};
    u16x8 h, l;
#pragma unroll
    for (int k = 0; k < 8; ++k) {
      const unsigned short hh = f2bf(xs[k]);
      h[k] = hh;
      l[k] = f2bf(xs[k] - bf2f(hh));
    }
    const int idx = row * 64 + (c0 ^ ((row & 7) << 3));
    *(u16x8*)(KV0 + idx) = h;
    *(u16x8*)(KV1 + idx) = l;
  }
  // N prefix (64 floats)
  if (tid < 64) {
    float np = tgp[4096 + tid];
    for (int cc = 0; cc < ccnt; ++cc) np += stb[(size_t)(g * 8 + cc) * STATE + 4096 + tid];
    NP[tid] = np;
  }

  float scq[4];
#pragma unroll
  for (int ri = 0; ri < 4; ++ri) {
    const int trow = w * 16 + ((lane & 48) >> 2) + ri;
    scq[ri] = ws[t0 + trow] * 0.125f;
  }
  __syncthreads();  // bar0: all staged

  // phiQ -> C_ in place; A-frags
  s16x8 aq[2];
  {
    f32x4 acc[4] = {};
    logits3(C_, D_, A_, B_, w, acc);
    phi_store_row(C_, acc, scq, w);
#pragma unroll
    for (int ks = 0; ks < 2; ++ks) aq[ks] = ld_frag(C_, w * 16, ks);
  }
  __syncthreads();  // bar1: proj + Ql fully consumed by all waves

  vtrans_half(A_, B_, F, tid, 0);       // proj dead -> VT hi/lo
  vtrans_half(A_, B_, F + 32 * 64, tid, 1);

  // A = phiQ . phiK^T, masked + quantized -> D_ (wave-local rows); row-sums rsI
  float rsI[4];
  {
    f32x4 accA[4] = {};
#pragma unroll
    for (int ct = 0; ct < 4; ++ct)
#pragma unroll
      for (int ks = 0; ks < 2; ++ks)
        accA[ct] = MFMA(aq[ks], ld_frag(PK, ct * 16, ks), accA[ct]);
#pragma unroll
    for (int ri = 0; ri < 4; ++ri) {
      const int t = w * 16 + ((lane & 48) >> 2) + ri;
      float part = 0.f;
#pragma unroll
      for (int ct = 0; ct < 4; ++ct) {
        const int j = ct * 16 + (lane & 15);
        const float a = (j <= t) ? accA[ct][ri] : 0.f;
        const unsigned short ah = f2bf(a);
        part += bf2f(ah);
        D_[t * 64 + (j ^ ((t & 7) << 3))] = ah;
      }
#pragma unroll
      for (int off = 1; off < 16; off <<= 1) part += __shfl_xor(part, off);
      rsI[ri] = part;
    }
  }
  __syncthreads();  // bar2: VT complete (D_/E is wave-local)

  // acc = A.(VTh+VTl)^T + phiQ.(KVh+KVl);  r = rsI + phiQ.Npref
  {
    s16x8 aA[2];
#pragma unroll
    for (int ks = 0; ks < 2; ++ks) aA[ks] = ld_frag(D_, w * 16, ks);
    f32x4 acc[4] = {};
#pragma unroll
    for (int ct = 0; ct < 4; ++ct) {
#pragma unroll
      for (int ks = 0; ks < 2; ++ks) {
        acc[ct] = MFMA(aA[ks], ld_frag(A_, ct * 16, ks), acc[ct]);
        acc[ct] = MFMA(aA[ks], ld_frag(B_, ct * 16, ks), acc[ct]);
        acc[ct] = MFMA(aq[ks], ld_frag(KV0, ct * 16, ks), acc[ct]);
        acc[ct] = MFMA(aq[ks], ld_frag(KV1, ct * 16, ks), acc[ct]);
      }
    }
    // r-prefix: dot(phiQ[t,:], NP) from the bf16 phiQ frags
    float rsp = 0.f;
#pragma unroll
    for (int ks = 0; ks < 2; ++ks) {
      const int m0 = ks * 32 + ((lane & 48) >> 1);
      const float4 n0 = *(const float4*)(NP + m0);
      const float4 n1 = *(const float4*)(NP + m0 + 4);
      const float nn[8] = {n0.x, n0.y, n0.z, n0.w, n1.x, n1.y, n1.z, n1.w};
#pragma unroll
      for (int i = 0; i < 8; ++i) rsp += bf2f((unsigned short)aq[ks][i]) * nn[i];
    }
    rsp += __shfl_xor(rsp, 16);
    rsp += __shfl_xor(rsp, 32);
    // rsp holds r_prefix for row t = w*16 + (lane&15); redistribute to C-row layout
#pragma unroll
    for (int ri = 0; ri < 4; ++ri) {
      const float r = rsI[ri] + __shfl(rsp, ((lane & 48) >> 2) + ri);
      const float inv = 1.f / (r + copysignf(1e-6f, r));
      const int t = w * 16 + ((lane & 48) >> 2) + ri;
#pragma unroll
      for (int ct = 0; ct < 4; ++ct) {
        out[tileBase + t * 64 + ct * 16 + (lane & 15)] = acc[ct][ri] * inv;
      }
    }
  }
}

extern "C" void kernel_launch(void* const* d_in, const int* in_sizes, int n_in,
                              void* d_out, int out_size, void* d_ws, size_t ws_size,
                              hipStream_t stream) {
  (void)in_sizes; (void)n_in; (void)out_size; (void)ws_size;
  const float* Q    = (const float*)d_in[0];
  const float* K    = (const float*)d_in[1];
  const float* V    = (const float*)d_in[2];
  const float* proj = (const float*)d_in[4];  // d_in[3] = sent_embed_slice (unused)
  float* out = (float*)d_out;
  float* ws  = (float*)d_ws;                  // [0,L): scaleQ, [L,2L): scaleK
  float* states = ws + 2 * LL;                // B*64*4160 f
  const size_t statesFloats = (size_t)BB * NCHUNK * STATE;
  float* tmp = states + statesFloats;         // B*8*4160 f (exclusive group prefix)
  const size_t tmpFloats = (size_t)BB * 8 * STATE;
  unsigned short* phiKg = (unsigned short*)(tmp + tmpFloats);  // 512*4096 u16 (4 MB)

  hipLaunchKernelGGL(k_scales, dim3(LL / 4), dim3(256), 0, stream, Q, K, ws);
  hipLaunchKernelGGL(k_chunk_sums, dim3(BB * NCHUNK), dim3(256), 0, stream,
                     K, V, proj, ws, states, phiKg);
  hipLaunchKernelGGL(k_groups, dim3((BB * STATE + 255) / 256), dim3(256), 0, stream, states, tmp);
  hipLaunchKernelGGL(k_out, dim3(BB * NCHUNK), dim3(256), 0, stream,
                     Q, V, proj, phiKg, ws, states, tmp, out);
}

// Round 11
// 34.040 us; speedup vs baseline: 7.5523x; 1.1347x over previous
//
#include <hip/hip_runtime.h>
#include <math.h>

// B=8, L=4096, D=64, M=64, masked=1 (fixed by setup_inputs)
#define BB 8
#define LL 4096
#define DD 64
#define SS 64
#define NCHUNK 64
#define STATE 4160  // 64x64 KV^T rows (d-major) + 64 N values

typedef __attribute__((ext_vector_type(8))) short s16x8;
typedef __attribute__((ext_vector_type(8))) unsigned short u16x8;
typedef __attribute__((ext_vector_type(4))) float f32x4;

#define MFMA(a, b, c) __builtin_amdgcn_mfma_f32_16x16x32_bf16((a), (b), (c), 0, 0, 0)

static __device__ __forceinline__ unsigned short f2bf(float x) {
  unsigned int u = __builtin_bit_cast(unsigned int, x);
  u += 0x7FFFu + ((u >> 16) & 1u);
  return (unsigned short)(u >> 16);
}
static __device__ __forceinline__ float bf2f(unsigned short h) {
  unsigned int u = ((unsigned int)h) << 16;
  return __builtin_bit_cast(float, u);
}

// LDS bf16 tile, row-major 64 cols, XOR-swizzled: elem (r,k) at r*64 + (k ^ ((r&7)<<3)).
// Frag: row r = row0 + (lane&15), k = ks*32 + (lane>>4)*8 .. +8.
static __device__ __forceinline__ s16x8 ld_frag(const unsigned short* base, int row0, int ks) {
  const int lane = threadIdx.x & 63;
  const int r = row0 + (lane & 15);
  const int idx = r * 64 + ((ks * 32 + ((lane & 48) >> 1)) ^ ((r & 7) << 3));
  return *(const s16x8*)(base + idx);
}

// Stage a 64x64 f32 global tile into hi/lo bf16 LDS tiles (swizzled). Coalesced.
static __device__ __forceinline__ void stage_hl(unsigned short* __restrict__ Sh,
                                                unsigned short* __restrict__ Sl,
                                                const float* __restrict__ src, int tid) {
#pragma unroll
  for (int it = 0; it < 2; ++it) {
    const int g = tid + it * 256;
    const int row = g >> 3;
    const int c0 = (g & 7) * 8;
    const float4 x0 = *(const float4*)(src + row * 64 + c0);
    const float4 x1 = *(const float4*)(src + row * 64 + c0 + 4);
    const float xs[8] = {x0.x, x0.y, x0.z, x0.w, x1.x, x1.y, x1.z, x1.w};
    u16x8 h, l;
#pragma unroll
    for (int k = 0; k < 8; ++k) {
      const unsigned short hh = f2bf(xs[k]);
      h[k] = hh;
      l[k] = f2bf(xs[k] - bf2f(hh));
    }
    const int idx = row * 64 + (c0 ^ ((row & 7) << 3));
    *(u16x8*)(Sh + idx) = h;
    *(u16x8*)(Sl + idx) = l;
  }
}

// Stage a linear bf16 [64][64] global image into a swizzled LDS tile. Coalesced.
static __device__ __forceinline__ void stage_img(unsigned short* __restrict__ S,
                                                 const unsigned short* __restrict__ src, int tid) {
#pragma unroll
  for (int it = 0; it < 2; ++it) {
    const int g = tid + it * 256;
    const int row = g >> 3;
    const int c0 = (g & 7) * 8;
    *(u16x8*)(S + row * 64 + (c0 ^ ((row & 7) << 3))) = *(const u16x8*)(src + row * 64 + c0);
  }
}

// Transpose 32 rows of the GLOBAL V tile directly into VT hi/lo bf16 tiles: VT[d][t] (swz).
// Lane d = tid&63 -> 64 consecutive floats per row read -> fully coalesced.
static __device__ __forceinline__ void vtrans_half_g(unsigned short* __restrict__ Gh,
                                                     unsigned short* __restrict__ Hl,
                                                     const float* __restrict__ Vt, int tid, int half) {
  const int d = tid & 63;
  const int tb = (tid >> 6) * 8;
  float v[8];
#pragma unroll
  for (int k = 0; k < 8; ++k) v[k] = Vt[(half * 32 + tb + k) * 64 + d];
  u16x8 hh, ll;
#pragma unroll
  for (int k = 0; k < 8; ++k) {
    const unsigned short h = f2bf(v[k]);
    hh[k] = h;
    ll[k] = f2bf(v[k] - bf2f(h));
  }
  const int idx = d * 64 + ((half * 32 + tb) ^ ((d & 7) << 3));
  *(u16x8*)(Gh + idx) = hh;
  *(u16x8*)(Hl + idx) = ll;
}

// 3-term split-precision logits: acc += Ah*Bh + Ah*Bl + Al*Bh  (wave row-tile w)
static __device__ __forceinline__ void logits3(const unsigned short* Ah_, const unsigned short* Al_,
                                               const unsigned short* Bh_, const unsigned short* Bl_,
                                               int w, f32x4 acc[4]) {
  s16x8 ah[2], al[2];
#pragma unroll
  for (int ks = 0; ks < 2; ++ks) {
    ah[ks] = ld_frag(Ah_, w * 16, ks);
    al[ks] = ld_frag(Al_, w * 16, ks);
  }
#pragma unroll
  for (int ct = 0; ct < 4; ++ct) {
#pragma unroll
    for (int ks = 0; ks < 2; ++ks) {
      const s16x8 bh = ld_frag(Bh_, ct * 16, ks);
      const s16x8 bl = ld_frag(Bl_, ct * 16, ks);
      acc[ct] = MFMA(ah[ks], bh, acc[ct]);
      acc[ct] = MFMA(ah[ks], bl, acc[ct]);
      acc[ct] = MFMA(al[ks], bh, acc[ct]);
    }
  }
}

// phi = exp(logit)*sc; store row-major [t][m] swizzled LDS image.
static __device__ __forceinline__ void phi_store_row(unsigned short* dst, const f32x4* acc,
                                                     const float* sc, int w) {
  const int lane = threadIdx.x & 63;
#pragma unroll
  for (int ri = 0; ri < 4; ++ri) {
    const int t = w * 16 + ((lane & 48) >> 2) + ri;
#pragma unroll
    for (int ct = 0; ct < 4; ++ct) {
      const int m = ct * 16 + (lane & 15);
      dst[t * 64 + (m ^ ((t & 7) << 3))] = f2bf(__expf(acc[ct][ri]) * sc[ri]);
    }
  }
}

// phi stored transposed [m][t] (swizzled).
static __device__ __forceinline__ void phi_store_col(unsigned short* dst, const f32x4* acc,
                                                     const float* sc, int w) {
  const int lane = threadIdx.x & 63;
#pragma unroll
  for (int ri = 0; ri < 4; ++ri) {
    const int t = w * 16 + ((lane & 48) >> 2) + ri;
#pragma unroll
    for (int ct = 0; ct < 4; ++ct) {
      const int m = ct * 16 + (lane & 15);
      dst[m * 64 + (t ^ ((m & 7) << 3))] = f2bf(__expf(acc[ct][ri]) * sc[ri]);
    }
  }
}

// ---------------- K1: per-timestep scales (vectorized) ----------------
__global__ __launch_bounds__(256) void k_scales(const float* __restrict__ Q,
                                                const float* __restrict__ K,
                                                float* __restrict__ ws) {
  const int t = blockIdx.x * 4 + (threadIdx.x >> 6);
  const int lane = threadIdx.x & 63;
  const int b = lane >> 3;
  const int d0 = (lane & 7) * 8;
  const size_t base = (size_t)b * (LL * DD) + (size_t)t * DD + d0;
  const float4 q0 = *(const float4*)(Q + base);
  const float4 q1 = *(const float4*)(Q + base + 4);
  const float4 k0 = *(const float4*)(K + base);
  const float4 k1 = *(const float4*)(K + base + 4);
  float sq = q0.x * q0.x + q0.y * q0.y + q0.z * q0.z + q0.w * q0.w +
             q1.x * q1.x + q1.y * q1.y + q1.z * q1.z + q1.w * q1.w;
  float sk = k0.x * k0.x + k0.y * k0.y + k0.z * k0.z + k0.w * k0.w +
             k1.x * k1.x + k1.y * k1.y + k1.z * k1.z + k1.w * k1.w;
#pragma unroll
  for (int off = 32; off; off >>= 1) {
    sq += __shfl_xor(sq, off);
    sk += __shfl_xor(sk, off);
  }
  if (lane == 0) {
    ws[t]      = expf(-0.5f * sqrtf(sq));
    ws[LL + t] = expf(-0.5f * sqrtf(sk));
  }
}

// ---------------- K2: phiK + per-chunk sums (64 KB LDS, no V scratch) ----------------
__global__ __launch_bounds__(256) void k_chunk_sums(const float* __restrict__ Kg,
                                                    const float* __restrict__ Vg,
                                                    const float* __restrict__ proj,
                                                    const float* __restrict__ ws,
                                                    float* __restrict__ states,
                                                    unsigned short* __restrict__ phiKg) {
  __shared__ unsigned short A_[4096], B_[4096];  // proj hi/lo
  __shared__ unsigned short C_[4096], D_[4096];  // K hi/lo
  __shared__ unsigned short E_[4096];            // phiK col [m][t] (swz)
  __shared__ unsigned short G_[4096], H_[4096];  // V^T hi/lo [d][t] (swz)
  __shared__ unsigned short R_[4096];            // phiK row image [t][m] (swz)
  const int tid = threadIdx.x;
  const int lane = tid & 63;
  const int w = tid >> 6;
  const int bc = blockIdx.x;
  const int b = bc >> 6;
  const int c = bc & (NCHUNK - 1);
  const int t0 = c * SS;
  const size_t tileBase = ((size_t)b * LL + t0) * DD;
  float* stc = states + ((size_t)b * NCHUNK + c) * (size_t)STATE;
  unsigned short* pkT = phiKg + (size_t)bc * 4096;

  stage_hl(A_, B_, proj, tid);
  stage_hl(C_, D_, Kg + tileBase, tid);
  float sck[4];
#pragma unroll
  for (int ri = 0; ri < 4; ++ri) {
    const int trow = w * 16 + ((lane & 48) >> 2) + ri;
    sck[ri] = ws[LL + t0 + trow] * 0.125f;  // * 1/sqrt(64)
  }
  __syncthreads();  // bar0: proj + K staged

  {  // phiK logits -> col image (LDS) + row image (LDS)
    f32x4 acc[4] = {};
    logits3(C_, D_, A_, B_, w, acc);
    phi_store_col(E_, acc, sck, w);
    phi_store_row(R_, acc, sck, w);
  }
  vtrans_half_g(G_, H_, Vg + tileBase, tid, 0);  // direct-global coalesced V reads
  vtrans_half_g(G_, H_, Vg + tileBase, tid, 1);
  __syncthreads();  // bar1: E_, R_, G_, H_ complete

  {  // coalesced de-swizzled copy of phiK row image to global
    const int r0 = tid >> 3;
    const int c0 = (tid & 7) * 8;
#pragma unroll
    for (int it = 0; it < 2; ++it) {
      const int r = r0 + it * 32;
      const int sidx = r * 64 + (c0 ^ ((r & 7) << 3));
      *(u16x8*)(pkT + r * 64 + c0) = *(const u16x8*)(R_ + sidx);
    }
  }
  {  // N[m] = colsum of quantized phiK
    const int m = tid >> 2, q = tid & 3;
    float s = 0.f;
#pragma unroll
    for (int p = 0; p < 2; ++p) {
      const int tt = q * 16 + p * 8;
      const u16x8 vv = *(const u16x8*)(E_ + m * 64 + (tt ^ ((m & 7) << 3)));
#pragma unroll
      for (int i = 0; i < 8; ++i) s += bf2f(vv[i]);
    }
    s += __shfl_xor(s, 1);
    s += __shfl_xor(s, 2);
    if (q == 0) stc[4096 + m] = s;
  }
  {  // KVT[d][m] = sum_t VT[d][t] * phiK[t][m]  (V hi/lo)
    s16x8 avh[2], avl[2];
#pragma unroll
    for (int ks = 0; ks < 2; ++ks) {
      avh[ks] = ld_frag(G_, w * 16, ks);
      avl[ks] = ld_frag(H_, w * 16, ks);
    }
    f32x4 acc[4] = {};
#pragma unroll
    for (int ct = 0; ct < 4; ++ct)
#pragma unroll
      for (int ks = 0; ks < 2; ++ks) {
        const s16x8 bp = ld_frag(E_, ct * 16, ks);
        acc[ct] = MFMA(avh[ks], bp, acc[ct]);
        acc[ct] = MFMA(avl[ks], bp, acc[ct]);
      }
#pragma unroll
    for (int ri = 0; ri < 4; ++ri) {
      const int d = w * 16 + ((lane & 48) >> 2) + ri;
#pragma unroll
      for (int ct = 0; ct < 4; ++ct) {
        stc[d * 64 + ct * 16 + (lane & 15)] = acc[ct][ri];
      }
    }
  }
}

// ---------------- K3: exclusive prefix over chunks (2-pass, R8-proven) ----------------
__global__ __launch_bounds__(256) void k_prefix1(const float* __restrict__ states,
                                                 float* __restrict__ tmp) {
  const int e = blockIdx.x * 256 + threadIdx.x;
  if (e >= BB * 8 * STATE) return;
  const int b = e / (8 * STATE);
  const int r = e % (8 * STATE);
  const int g = r / STATE;
  const int el = r % STATE;
  const float* p = states + ((size_t)b * NCHUNK + g * 8) * STATE + el;
  float s = 0.f;
#pragma unroll
  for (int i = 0; i < 8; ++i) s += p[(size_t)i * STATE];
  tmp[((size_t)b * 8 + g) * STATE + el] = s;
}

__global__ __launch_bounds__(256) void k_prefix2(float* __restrict__ states,
                                                 const float* __restrict__ tmp) {
  const int e = blockIdx.x * 256 + threadIdx.x;
  if (e >= BB * 8 * STATE) return;
  const int b = e / (8 * STATE);
  const int r = e % (8 * STATE);
  const int g = r / STATE;
  const int el = r % STATE;
  float run = 0.f;
  for (int g2 = 0; g2 < g; ++g2) run += tmp[((size_t)b * 8 + g2) * STATE + el];
  float* p = states + ((size_t)b * NCHUNK + g * 8) * STATE + el;
#pragma unroll
  for (int i = 0; i < 8; ++i) {
    const float v = p[(size_t)i * STATE];
    p[(size_t)i * STATE] = run;
    run += v;
  }
}

// ---------------- K4: outputs (56 KB LDS, no V scratch) ----------------
__global__ __launch_bounds__(256) void k_out(const float* __restrict__ Qg,
                                             const float* __restrict__ Vg,
                                             const float* __restrict__ proj,
                                             const unsigned short* __restrict__ phiKg,
                                             const float* __restrict__ ws,
                                             const float* __restrict__ states,
                                             float* __restrict__ out) {
  __shared__ unsigned short A_[4096], B_[4096];  // proj hi/lo -> VT hi/lo
  __shared__ unsigned short C_[4096];            // Qh -> phiQ image [t][m]
  __shared__ unsigned short D_[4096];            // Ql -> E (masked quantized A)
  __shared__ unsigned short PK[4096];            // phiK image [j][m] (swz)
  __shared__ unsigned short KV0[4096], KV1[4096];// KV prefix hi/lo [d][m]
  const int tid = threadIdx.x;
  const int lane = tid & 63;
  const int w = tid >> 6;
  const int bc = blockIdx.x;
  const int b = bc >> 6;
  const int c = bc & (NCHUNK - 1);
  const int t0 = c * SS;
  const size_t tileBase = ((size_t)b * LL + t0) * DD;
  const float* st = states + ((size_t)b * NCHUNK + c) * (size_t)STATE;
  const unsigned short* pkT = phiKg + (size_t)bc * 4096;

  stage_hl(A_, B_, proj, tid);
  stage_hl(C_, D_, Qg + tileBase, tid);
  stage_img(PK, pkT, tid);
  stage_hl(KV0, KV1, st, tid);
  float scq[4];
#pragma unroll
  for (int ri = 0; ri < 4; ++ri) {
    const int trow = w * 16 + ((lane & 48) >> 2) + ri;
    scq[ri] = ws[t0 + trow] * 0.125f;
  }
  __syncthreads();  // bar0: all staged

  // phiQ -> C_ in place; A-frags
  s16x8 aq[2];
  {
    f32x4 acc[4] = {};
    logits3(C_, D_, A_, B_, w, acc);
    phi_store_row(C_, acc, scq, w);
#pragma unroll
    for (int ks = 0; ks < 2; ++ks) aq[ks] = ld_frag(C_, w * 16, ks);
  }
  __syncthreads();  // bar1: proj + Ql fully consumed by all waves

  vtrans_half_g(A_, B_, Vg + tileBase, tid, 0);  // proj dead -> VT hi/lo (coalesced global V)
  vtrans_half_g(A_, B_, Vg + tileBase, tid, 1);

  // A = phiQ . phiK^T, masked + quantized -> D_ (wave-local rows); row-sums rsI
  float rsI[4];
  {
    f32x4 accA[4] = {};
#pragma unroll
    for (int ct = 0; ct < 4; ++ct)
#pragma unroll
      for (int ks = 0; ks < 2; ++ks)
        accA[ct] = MFMA(aq[ks], ld_frag(PK, ct * 16, ks), accA[ct]);
#pragma unroll
    for (int ri = 0; ri < 4; ++ri) {
      const int t = w * 16 + ((lane & 48) >> 2) + ri;
      float part = 0.f;
#pragma unroll
      for (int ct = 0; ct < 4; ++ct) {
        const int j = ct * 16 + (lane & 15);
        const float a = (j <= t) ? accA[ct][ri] : 0.f;
        const unsigned short ah = f2bf(a);
        part += bf2f(ah);
        D_[t * 64 + (j ^ ((t & 7) << 3))] = ah;
      }
#pragma unroll
      for (int off = 1; off < 16; off <<= 1) part += __shfl_xor(part, off);
      rsI[ri] = part;
    }
  }
  __syncthreads();  // bar2: VT complete (D_/E is wave-local)

  // acc = A.(VTh+VTl)^T + phiQ.(KVh+KVl);  r = rsI + phiQ.Npref
  {
    s16x8 aA[2];
#pragma unroll
    for (int ks = 0; ks < 2; ++ks) aA[ks] = ld_frag(D_, w * 16, ks);
    f32x4 acc[4] = {};
#pragma unroll
    for (int ct = 0; ct < 4; ++ct) {
#pragma unroll
      for (int ks = 0; ks < 2; ++ks) {
        acc[ct] = MFMA(aA[ks], ld_frag(A_, ct * 16, ks), acc[ct]);
        acc[ct] = MFMA(aA[ks], ld_frag(B_, ct * 16, ks), acc[ct]);
        acc[ct] = MFMA(aq[ks], ld_frag(KV0, ct * 16, ks), acc[ct]);
        acc[ct] = MFMA(aq[ks], ld_frag(KV1, ct * 16, ks), acc[ct]);
      }
    }
    // r-prefix: dot(phiQ[t,:], Npref) from the bf16 phiQ frags
    float rsp = 0.f;
    const float* Np = st + 4096;
#pragma unroll
    for (int ks = 0; ks < 2; ++ks) {
      const int m0 = ks * 32 + ((lane & 48) >> 1);
      const float4 n0 = *(const float4*)(Np + m0);
      const float4 n1 = *(const float4*)(Np + m0 + 4);
      const float nn[8] = {n0.x, n0.y, n0.z, n0.w, n1.x, n1.y, n1.z, n1.w};
#pragma unroll
      for (int i = 0; i < 8; ++i) rsp += bf2f((unsigned short)aq[ks][i]) * nn[i];
    }
    rsp += __shfl_xor(rsp, 16);
    rsp += __shfl_xor(rsp, 32);
    // rsp holds r_prefix for row t = w*16 + (lane&15); redistribute to C-row layout
#pragma unroll
    for (int ri = 0; ri < 4; ++ri) {
      const float r = rsI[ri] + __shfl(rsp, ((lane & 48) >> 2) + ri);
      const float inv = 1.f / (r + copysignf(1e-6f, r));
      const int t = w * 16 + ((lane & 48) >> 2) + ri;
#pragma unroll
      for (int ct = 0; ct < 4; ++ct) {
        out[tileBase + t * 64 + ct * 16 + (lane & 15)] = acc[ct][ri] * inv;
      }
    }
  }
}

extern "C" void kernel_launch(void* const* d_in, const int* in_sizes, int n_in,
                              void* d_out, int out_size, void* d_ws, size_t ws_size,
                              hipStream_t stream) {
  (void)in_sizes; (void)n_in; (void)out_size; (void)ws_size;
  const float* Q    = (const float*)d_in[0];
  const float* K    = (const float*)d_in[1];
  const float* V    = (const float*)d_in[2];
  const float* proj = (const float*)d_in[4];  // d_in[3] = sent_embed_slice (unused)
  float* out = (float*)d_out;
  float* ws  = (float*)d_ws;                  // [0,L): scaleQ, [L,2L): scaleK
  float* states = ws + 2 * LL;                // B*64*4160 f
  const size_t statesFloats = (size_t)BB * NCHUNK * STATE;
  float* tmp = states + statesFloats;         // B*8*4160 f
  const size_t tmpFloats = (size_t)BB * 8 * STATE;
  unsigned short* phiKg = (unsigned short*)(tmp + tmpFloats);  // 512*4096 u16 (4 MB)

  hipLaunchKernelGGL(k_scales, dim3(LL / 4), dim3(256), 0, stream, Q, K, ws);
  hipLaunchKernelGGL(k_chunk_sums, dim3(BB * NCHUNK), dim3(256), 0, stream,
                     K, V, proj, ws, states, phiKg);
  hipLaunchKernelGGL(k_prefix1, dim3((BB * 8 * STATE + 255) / 256), dim3(256), 0, stream, states, tmp);
  hipLaunchKernelGGL(k_prefix2, dim3((BB * 8 * STATE + 255) / 256), dim3(256), 0, stream, states, tmp);
  hipLaunchKernelGGL(k_out, dim3(BB * NCHUNK), dim3(256), 0, stream,
                     Q, V, proj, phiKg, ws, states, out);
}